// Round 7
// baseline (392.680 us; speedup 1.0000x reference)
//
#include <hip/hip_runtime.h>

// VQ-VAE quantizer: x [B=32, C=64, T=4096] f32, emb [K=1024, D=64] f32.
// Outputs flat f32: quant_out [B*C*T], codebook_loss [1], commitment_loss [1],
// idx [B*T] (written as float).
//
// CORRECTNESS-CRITICAL (validated R2/R4/R5/R6, absmax 3.8e-6 = 0 argmin flips):
// checker recomputes the reference with numpy in f32. d = (S+e2[k])-2*dot is
// ~64 -> quantized at ulp(64)=7.6e-6; top-2 core gaps are ~4e-6..4e-3 (emb is
// tiny: U(-1/1024,1/1024)), so many rows tie at the grid and the argmin is
// decided by numpy's exact rounding. Replicated bit-for-bit:
//   S, e2[k]: numpy pairwise_sum of fl(v*v), n=64 (8 accs stride-8, then
//             ((r0+r1)+(r2+r3))+((r4+r5)+(r6+r7)); mul/add separately rounded)
//   dot     : per-candidate single-accumulator FMA chain, i ascending (BLAS)
//   d       : fl(fl(S+e2[k]) - 2*dot)  via fma(-2,dot,S+e2) (2*dot exact)
//   argmin  : strict <, ascending k; cross-slice merge via packed u64
//             (bits(d)<<10 | k) — d>0 so bit order == value order.
// DO NOT change chain arithmetic/ordering. DO NOT split D within a chain.
//
// Perf history:
//   R2 453us: x[64] "in regs" -> remat'd global loads in-loop (VGPR 44).
//   R3 1017us: dynamic xr index -> scratch; non-uniform ks -> VMEM emb.
//   R4 369us: asm-pinned xr -> AGPR shunt; VALU = 3x floor (accvgpr traffic).
//   R5 828us: NR=16 regs + token'd re-stream -> d[16] spilled (WRITE +35MB).
//   R6 325us: x in LDS (stride 65, conflict-free), emb via s_load. VALUBusy
//       77% but busy-time 250us >> 167us achieved-FMA floor: emb scalar path
//       (256 s_load_x4/chunk, K$ thrash, s_load+ds_read share lgkmcnt) is the
//       drag. SGPR=112 (full) corroborates.
//   R7: emb -> per-wave LDS chunks (4KB, double-buffered, wave-local: no
//       barriers). Inner loop reads emb via ds_read_b128 at wave-uniform
//       addr = broadcast, conflict-free; FMA operands all-VGPR; staging on
//       vmcnt (decoupled from lgkm). Live regs ~30-45.

#define KCB 1024
#define DD 64
#define BB 32
#define TT 4096
#define BT (BB * TT)            // 131072 rows
#define NELEM (BB * DD * TT)    // 8388608

#define KSPLIT 4
#define KPER (KCB / KSPLIT)     // 256 candidates per wave
#define NR 16                   // candidates per k-chunk
#define NCHUNK (KPER / NR)      // 16 chunks per wave
#define ROWS_PER_BLOCK 64
#define XSTRIDE 65              // odd -> (r+i)%32 banking, 2 lanes/bank = free
#define ECHUNK (NR * DD)        // 1024 floats = 4KB per emb chunk

#define WS_LOSS 0
#define WS_E2 64

// e2[k] = numpy pairwise sum of fl(e_i*e_i); also zero the loss accumulator.
__global__ void vq_compute_e2(const float* __restrict__ emb, float* __restrict__ ws) {
#pragma clang fp contract(off)
    int k = blockIdx.x * blockDim.x + threadIdx.x;
    if (k == 0) ws[WS_LOSS] = 0.0f;
    if (k < KCB) {
        const float* e = emb + (size_t)k * DD;
        float r[8];
#pragma unroll
        for (int j = 0; j < 8; ++j) r[j] = e[j] * e[j];
#pragma unroll
        for (int i = 8; i < 64; i += 8) {
#pragma unroll
            for (int j = 0; j < 8; ++j) r[j] += e[i + j] * e[i + j];
        }
        ws[WS_E2 + k] = ((r[0] + r[1]) + (r[2] + r[3])) + ((r[4] + r[5]) + (r[6] + r[7]));
    }
}

__launch_bounds__(256, 4)
__global__ void vq_main(const float* __restrict__ x, const float* __restrict__ emb,
                        float* __restrict__ out, float* __restrict__ ws) {
#pragma clang fp contract(off)
    const int tid = threadIdx.x;
    const int lane = tid & 63;                                // row-within-block
    const int ks = __builtin_amdgcn_readfirstlane(tid >> 6);  // k-slice, SGPR

    const int row0 = blockIdx.x * ROWS_PER_BLOCK;             // 64 | 4096 -> b uniform
    const int b = row0 >> 12;
    const int t0 = row0 & (TT - 1);
    const int row = row0 + lane;

    __shared__ float x_lds[ROWS_PER_BLOCK * XSTRIDE];
    __shared__ __align__(16) float e_lds[KSPLIT * 2 * ECHUNK];  // per-wave dbuf
    __shared__ unsigned long long redu[ROWS_PER_BLOCK];
    __shared__ float bsum;
    if (tid < ROWS_PER_BLOCK) redu[tid] = ~0ull;
    if (tid == 0) bsum = 0.0f;

    // Stage x-slice: wave ks loads channels c = 4j+ks; global coalesced,
    // LDS write (r+c)%32 conflict-free.
    const float* xg = x + (size_t)b * DD * TT + t0 + lane;
#pragma unroll
    for (int j = 0; j < DD / KSPLIT; ++j) {
        const int c = 4 * j + ks;
        x_lds[lane * XSTRIDE + c] = xg[(size_t)c * TT];
    }
    __syncthreads();

    // S = numpy pairwise sum of fl(x_i*x_i), n=64 (from LDS, conflict-free).
    const int xbase = lane * XSTRIDE;
    float r[8];
#pragma unroll
    for (int j = 0; j < 8; ++j) { float v = x_lds[xbase + j]; r[j] = v * v; }
#pragma unroll
    for (int i = 8; i < 64; i += 8) {
#pragma unroll
        for (int j = 0; j < 8; ++j) { float v = x_lds[xbase + i + j]; r[j] += v * v; }
    }
    const float S = ((r[0] + r[1]) + (r[2] + r[3])) + ((r[4] + r[5]) + (r[6] + r[7]));

    const float* e2p = ws + WS_E2;

    float best = 3.4e38f;
    int bidx = 0;

    const int k0 = ks * KPER;
    // emb chunk staging: wave-local double buffer; lane l covers 16B at
    // float-offset j*256 + 4l (j=0..3) of the 4KB chunk. Coalesced global,
    // 2-way (free) LDS write banking. Wave-local LDS => no barriers needed.
    float* ebuf0 = e_lds + (size_t)ks * 2 * ECHUNK;
    const float4* eg0 = (const float4*)(emb + (size_t)k0 * DD);

    // preload chunk 0 into regs
    float4 pre[4];
#pragma unroll
    for (int j = 0; j < 4; ++j) pre[j] = eg0[j * 64 + lane];

#pragma unroll 1
    for (int kk = 0; kk < KPER; kk += NR) {
        const int kb = k0 + kk;
        float* ebuf = ebuf0 + ((kk / NR) & 1) * ECHUNK;

        // commit prefetched chunk to LDS, then prefetch next chunk
        float4* ew = (float4*)ebuf;
#pragma unroll
        for (int j = 0; j < 4; ++j) ew[j * 64 + lane] = pre[j];
        if (kk + NR < KPER) {
            const float4* egn = (const float4*)(emb + (size_t)(kb + NR) * DD);
#pragma unroll
            for (int j = 0; j < 4; ++j) pre[j] = egn[j * 64 + lane];
        }

        // Opaque zero index: x_lds addresses differ symbolically per kk iter
        // -> no CSE/hoist of x values across the k-loop (R2 pathology).
        int xo = 0;
        asm volatile("" : "+v"(xo));

        float d[NR];
#pragma unroll
        for (int c = 0; c < NR; ++c) d[c] = 0.0f;

#pragma unroll
        for (int ih = 0; ih < DD / 4; ++ih) {
            float xv0 = x_lds[xbase + xo + 4 * ih + 0];
            float xv1 = x_lds[xbase + xo + 4 * ih + 1];
            float xv2 = x_lds[xbase + xo + 4 * ih + 2];
            float xv3 = x_lds[xbase + xo + 4 * ih + 3];
            // Per-candidate chain: i ascending (ih outer) — bit-equal to the
            // sequential BLAS dot. emb reads: uniform addr b128 broadcast.
#pragma unroll
            for (int c = 0; c < NR; ++c) {
                float4 e = *(const float4*)(ebuf + c * DD + 4 * ih);
                float acc = d[c];
                acc = __builtin_fmaf(e.x, xv0, acc);
                acc = __builtin_fmaf(e.y, xv1, acc);
                acc = __builtin_fmaf(e.z, xv2, acc);
                acc = __builtin_fmaf(e.w, xv3, acc);
                d[c] = acc;
            }
        }

#pragma unroll
        for (int c = 0; c < NR; ++c) {
            float tt = S + e2p[kb + c];                 // fl(S + e2)
            float s = __builtin_fmaf(-2.0f, d[c], tt);  // fl(tt - 2*dot)
            if (s < best) { best = s; bidx = kb + c; }  // strict <, ascending k
        }
    }

    // Merge 4 slices: packed (bits(d)<<10 | k); d>0 => bit-monotone; low bits
    // give numpy first-index tie-break.
    unsigned long long packed =
        ((unsigned long long)__float_as_uint(best) << 10) | (unsigned int)bidx;
    atomicMin(&redu[lane], packed);
    __syncthreads();

    const int fidx = (int)(redu[lane] & 1023u);

    // Epilogue: 4-way dim split via wave-uniform branches; x re-read from LDS.
    const float* eql = emb + (size_t)fidx * DD;
    float* oq = out + (size_t)b * DD * TT + t0 + lane;
    float lsum = 0.0f;
#pragma unroll
    for (int c4 = 0; c4 < DD / 4; ++c4) {
        if (ks == (c4 >> 2)) {   // uniform: s_cmp + s_cbranch
            float4 v = *(const float4*)(eql + 4 * c4);
            oq[(size_t)(4 * c4 + 0) * TT] = v.x;
            oq[(size_t)(4 * c4 + 1) * TT] = v.y;
            oq[(size_t)(4 * c4 + 2) * TT] = v.z;
            oq[(size_t)(4 * c4 + 3) * TT] = v.w;
            float a0 = v.x - x_lds[xbase + 4 * c4 + 0];
            float a1 = v.y - x_lds[xbase + 4 * c4 + 1];
            float a2 = v.z - x_lds[xbase + 4 * c4 + 2];
            float a3 = v.w - x_lds[xbase + 4 * c4 + 3];
            lsum = __builtin_fmaf(a0, a0, lsum);
            lsum = __builtin_fmaf(a1, a1, lsum);
            lsum = __builtin_fmaf(a2, a2, lsum);
            lsum = __builtin_fmaf(a3, a3, lsum);
        }
    }

    if (ks == 0) out[NELEM + 2 + row] = (float)fidx;

    // wave(64) shuffle reduction, LDS-stage, one global atomic per block
#pragma unroll
    for (int off = 32; off > 0; off >>= 1) lsum += __shfl_down(lsum, off);
    if (lane == 0) atomicAdd(&bsum, lsum);
    __syncthreads();
    if (tid == 0) atomicAdd(ws + WS_LOSS, bsum);
}

__global__ void vq_finalize(const float* __restrict__ ws, float* __restrict__ out) {
    if (threadIdx.x == 0 && blockIdx.x == 0) {
        float M = ws[WS_LOSS] / (float)NELEM;
        out[NELEM + 0] = M;           // codebook_loss
        out[NELEM + 1] = 0.25f * M;   // commitment_loss = BETA * same mean
    }
}

extern "C" void kernel_launch(void* const* d_in, const int* in_sizes, int n_in,
                              void* d_out, int out_size, void* d_ws, size_t ws_size,
                              hipStream_t stream) {
    const float* x = (const float*)d_in[0];
    const float* emb = (const float*)d_in[1];
    float* out = (float*)d_out;
    float* ws = (float*)d_ws;

    vq_compute_e2<<<KCB / 256, 256, 0, stream>>>(emb, ws);
    vq_main<<<BT / ROWS_PER_BLOCK, 256, 0, stream>>>(x, emb, out, ws);
    vq_finalize<<<1, 64, 0, stream>>>(ws, out);
}